// Round 6
// baseline (323.429 us; speedup 1.0000x reference)
//
#include <hip/hip_runtime.h>

typedef __bf16 bf16;
typedef __attribute__((ext_vector_type(8))) __bf16 bf16x8;
typedef __attribute__((ext_vector_type(4))) float f32x4;

// async global->LDS, 16B per lane. LDS dest must be wave-uniform base; HW writes
// base + lane*16. Swizzled layouts are achieved by pre-swizzling the global src.
__device__ __forceinline__ void gload_lds16(const void* g, void* l) {
  __builtin_amdgcn_global_load_lds(
      (const __attribute__((address_space(1))) unsigned int*)(g),
      (__attribute__((address_space(3))) unsigned int*)(l),
      16, 0, 0);
}

__device__ __forceinline__ float exp2_hw(float x) {  // v_exp_f32 = 2^x, pure VALU asm
  float r; asm("v_exp_f32 %0, %1" : "=v"(r) : "v"(x)); return r;
}
__device__ __forceinline__ unsigned cvtpk_bf16(float a, float b) {  // lo=a, hi=b
  unsigned r; asm("v_cvt_pk_bf16_f32 %0, %1, %2" : "=v"(r) : "v"(a), "v"(b)); return r;
}

// ---------------- pack kernels ----------------

// resid fp32 -> bf16, vectorized 8/thread. n = 8388608 = 4096*256*8 exactly.
__global__ __launch_bounds__(256) void pack_x(const float* __restrict__ x, bf16* __restrict__ o) {
  int i = (blockIdx.x * 256 + threadIdx.x) * 8;
  float4 a = *(const float4*)(x + i);
  float4 b = *(const float4*)(x + i + 4);
  bf16x8 v;
  v[0] = (bf16)a.x; v[1] = (bf16)a.y; v[2] = (bf16)a.z; v[3] = (bf16)a.w;
  v[4] = (bf16)b.x; v[5] = (bf16)b.y; v[6] = (bf16)b.z; v[7] = (bf16)b.w;
  *(bf16x8*)(o + i) = v;
}

// W_{Q,K,V}[h][k][d] (fp32) -> Wt[n=p*1024+h*64+d][k] (bf16, B^T layout), 64x64 LDS transpose tiles.
__global__ __launch_bounds__(256) void pack_w(const float* __restrict__ WQ, const float* __restrict__ WK,
                                              const float* __restrict__ WV, bf16* __restrict__ Wt) {
  int bid = blockIdx.x;                 // 768 = 3 * 16h * 16k-tiles
  int p = bid >> 8, h = (bid >> 4) & 15, k0 = (bid & 15) * 64;
  const float* src = (p == 0 ? WQ : p == 1 ? WK : WV) + h * 65536;
  __shared__ float tile[64][65];
  int t = threadIdx.x, c = t & 63, r4 = t >> 6;
#pragma unroll
  for (int rr = 0; rr < 16; ++rr) {
    int k = r4 + rr * 4;
    tile[k][c] = src[(k0 + k) * 64 + c];   // coalesced read along d
  }
  __syncthreads();
#pragma unroll
  for (int rr = 0; rr < 16; ++rr) {
    int d = r4 + rr * 4;
    Wt[(p * 1024 + h * 64 + d) * 1024 + k0 + c] = (bf16)tile[c][d];  // coalesced write along k
  }
}

// W_O viewed as [hd=1024][m=1024] -> Wo_t[m][hd]
__global__ __launch_bounds__(256) void pack_wo(const float* __restrict__ WO, bf16* __restrict__ Wt) {
  int bid = blockIdx.x;                 // 256 = 16 hd-tiles * 16 m-tiles
  int r0 = (bid >> 4) * 64, c0 = (bid & 15) * 64;
  __shared__ float tile[64][65];
  int t = threadIdx.x, c = t & 63, r4 = t >> 6;
#pragma unroll
  for (int rr = 0; rr < 16; ++rr) {
    int r = r4 + rr * 4;
    tile[r][c] = WO[(r0 + r) * 1024 + c0 + c];
  }
  __syncthreads();
#pragma unroll
  for (int rr = 0; rr < 16; ++rr) {
    int m = r4 + rr * 4;
    Wt[(c0 + m) * 1024 + r0 + c] = (bf16)tile[c][m];
  }
}

__global__ __launch_bounds__(256) void pack_bias(const float* __restrict__ bQ, const float* __restrict__ bK,
                                                 const float* __restrict__ bV, float* __restrict__ o) {
  int i = blockIdx.x * 256 + threadIdx.x;
  if (i < 3072) {
    int p = i >> 10, j = i & 1023;
    o[i] = (p == 0 ? bQ : p == 1 ? bK : bV)[j];
  }
}

// ---------------- GEMM: C[M,N] = A[M,K] * Bt[N,K]^T + bias ----------------
template <int OUTF32>
__global__ __launch_bounds__(256, 2) void gemm_bt(const bf16* __restrict__ A, const bf16* __restrict__ Bt,
                                                  const float* __restrict__ bias, void* __restrict__ Cv,
                                                  int M, int N, int K) {
  __shared__ bf16 As[128 * 64];
  __shared__ bf16 Bs[128 * 64];
  int tid = threadIdx.x;
  int wv = tid >> 6, ln = tid & 63, lr = ln & 15, lh = ln >> 4;
  int wr = wv >> 1, wc = wv & 1;
  int row0 = blockIdx.y * 128, col0 = blockIdx.x * 128;
  int ss = (ln & 7) ^ (ln >> 3);
  const char* ga = (const char*)(A + (long)(row0 + wv * 32 + (ln >> 3)) * K) + ss * 16;
  const char* gb = (const char*)(Bt + (long)(col0 + wv * 32 + (ln >> 3)) * K) + ss * 16;
  long rowskip = (long)8 * K * 2;
  f32x4 acc[4][4] = {};
  for (int k0 = 0; k0 < K; k0 += 64) {
#pragma unroll
    for (int i = 0; i < 4; ++i) {
      gload_lds16(ga + (long)k0 * 2 + i * rowskip, (char*)As + (wv * 32 + i * 8) * 128);
      gload_lds16(gb + (long)k0 * 2 + i * rowskip, (char*)Bs + (wv * 32 + i * 8) * 128);
    }
    __syncthreads();
    bf16x8 af[4][2], bfr[4][2];
#pragma unroll
    for (int mi = 0; mi < 4; ++mi)
#pragma unroll
      for (int ks = 0; ks < 2; ++ks) {
        int row = wr * 64 + mi * 16 + lr;
        int o = row * 128 + (((ks * 4 + lh) ^ (row & 7)) << 4);
        af[mi][ks] = *(const bf16x8*)((const char*)As + o);
      }
#pragma unroll
    for (int ni = 0; ni < 4; ++ni)
#pragma unroll
      for (int ks = 0; ks < 2; ++ks) {
        int row = wc * 64 + ni * 16 + lr;
        int o = row * 128 + (((ks * 4 + lh) ^ (row & 7)) << 4);
        bfr[ni][ks] = *(const bf16x8*)((const char*)Bs + o);
      }
    __builtin_amdgcn_s_setprio(1);
#pragma unroll
    for (int ks = 0; ks < 2; ++ks)
#pragma unroll
      for (int mi = 0; mi < 4; ++mi)
#pragma unroll
        for (int ni = 0; ni < 4; ++ni)
          acc[mi][ni] = __builtin_amdgcn_mfma_f32_16x16x32_bf16(af[mi][ks], bfr[ni][ks], acc[mi][ni], 0, 0, 0);
    __builtin_amdgcn_s_setprio(0);
    __syncthreads();
  }
#pragma unroll
  for (int mi = 0; mi < 4; ++mi) {
    int row = row0 + wr * 64 + mi * 16 + lh * 4;
#pragma unroll
    for (int ni = 0; ni < 4; ++ni) {
      int col = col0 + wc * 64 + ni * 16 + lr;
      float bvv = bias[col];
#pragma unroll
      for (int r = 0; r < 4; ++r) {
        float v = acc[mi][ni][r] + bvv;
        if (OUTF32) ((float*)Cv)[(long)(row + r) * N + col] = v;
        else        ((bf16*)Cv)[(long)(row + r) * N + col] = (bf16)v;
      }
    }
  }
}

// ---------------- flash attention (swapped-operand, balanced pairs) ----------------
// grid = 1024 = 64 bh * 16 pairs. Each block: 4 waves x 16 q-rows = 64-row q-tile,
// processes TWO q-tiles sequentially: qt64 = pair and 31-pair -> exactly 33 kv-tile
// units per block (perfect balance, sustained 4 blocks/CU residency).
// S^T = mfma(A=K, B=Q): lane owns q=lr, 16 kv regs -> in-register softmax reduce.
// K direct from global (L2-resident). V^T in LDS double-buffered. P via per-wave
// swizzled LDS tile. PV = mfma(A=V^T, B=P^T) -> O^T, lane-local l.
// Defer-max (T13, THR=8 log2-domain): skip oa-rescale when max growth small.
__global__ __launch_bounds__(256, 4) void flash(const bf16* __restrict__ Qkv, bf16* __restrict__ Z) {
  __shared__ bf16 Vt[2][64 * 64];        // [d][kv] V^T, swizzle f(d)=(d&7)^(d>>3)
  __shared__ unsigned char Pl[4][2048];  // per-wave P[q=16][kv=64] bf16, swizzle row&7
  const float SCALE = 0.1803368867f;     // 0.125 * log2(e)
  const float MASKV = -144269.5041f;     // -1e5 * log2(e)
  int bid = blockIdx.x;
  int pair = bid >> 6;                         // 0..15
  int bh = (bid & 7) * 8 + ((bid >> 3) & 7);   // same-bh -> same XCD (bid%8)
  int b = bh >> 4, h = bh & 15;
  int tid = threadIdx.x;
  int wv = tid >> 6, ln = tid & 63, lr = ln & 15, lh = ln >> 4;
  const bf16* Qg = Qkv + (long)b * 2048 * 3072 + h * 64;
  const bf16* Kg = Qg + 1024;
  const bf16* Vg = Qg + 2048;
  int vs0 = (tid >> 3) * 2, vd0 = (tid & 7) * 8;
  char* pw = (char*)Pl[wv];

  bf16x8 v0, v1;
  auto loadV = [&](int kvrow0) {
    v0 = *(const bf16x8*)(Vg + (long)(kvrow0 + vs0) * 3072 + vd0);
    v1 = *(const bf16x8*)(Vg + (long)(kvrow0 + vs0 + 1) * 3072 + vd0);
  };
  auto writeV = [&](bf16* vd) {
#pragma unroll
    for (int j = 0; j < 8; ++j) {
      int d = vd0 + j;
      int o = (d * 128 + vs0 * 2) ^ ((((d & 7) ^ (d >> 3)) & 7) << 4);
      unsigned int pk = (unsigned int)__builtin_bit_cast(unsigned short, (bf16)v0[j])
                      | ((unsigned int)__builtin_bit_cast(unsigned short, (bf16)v1[j]) << 16);
      *(unsigned int*)((char*)vd + o) = pk;
    }
  };

#pragma unroll 1
  for (int half = 0; half < 2; ++half) {
    int qt = half ? 31 - pair : pair;     // paired q-tiles: work = (qt+1)+(32-qt-1)... = 33 const
    int q0 = qt * 64;
    int nt = qt + 1;
    // prologue: stage V tile 0, load Q frags for this q-tile
    loadV(0);
    bf16x8 bq[2];
#pragma unroll
    for (int ks = 0; ks < 2; ++ks)
      bq[ks] = *(const bf16x8*)(Qg + (long)(q0 + wv * 16 + lr) * 3072 + ks * 32 + lh * 8);
    writeV(Vt[0]);
    __syncthreads();

    f32x4 oa[4] = {};                     // oa[n2=dblk]: O^T[d][q=lr]
    float m_st = -1e30f, l_st = 0.f;
    int cur = 0;
    for (int t = 0; t < nt; ++t) {
      int kv0 = t * 64;
      bool more = (t + 1 < nt);
      // K A-frags direct from global (L2-hot)
      bf16x8 kf[4][2];
#pragma unroll
      for (int n = 0; n < 4; ++n)
#pragma unroll
        for (int ks = 0; ks < 2; ++ks)
          kf[n][ks] = *(const bf16x8*)(Kg + (long)(kv0 + n * 16 + lr) * 3072 + ks * 32 + lh * 8);
      if (more) loadV(kv0 + 64);
      // S^T = K * Q^T : D[row=kv][col=q]
      f32x4 sc[4];
      __builtin_amdgcn_s_setprio(1);
#pragma unroll
      for (int n = 0; n < 4; ++n) {
        f32x4 zacc = {0.f, 0.f, 0.f, 0.f};
        zacc = __builtin_amdgcn_mfma_f32_16x16x32_bf16(kf[n][0], bq[0], zacc, 0, 0, 0);
        zacc = __builtin_amdgcn_mfma_f32_16x16x32_bf16(kf[n][1], bq[1], zacc, 0, 0, 0);
        sc[n] = zacc;
      }
      __builtin_amdgcn_s_setprio(0);
      // scale (base-2)
#pragma unroll
      for (int n = 0; n < 4; ++n)
#pragma unroll
        for (int r = 0; r < 4; ++r) sc[n][r] *= SCALE;
      // causal mask: only the single diagonal tile (t==nt-1), uniform branch
      if (t == nt - 1) {
        int qrow = q0 + wv * 16 + lr;
#pragma unroll
        for (int n = 0; n < 4; ++n) {
          int kvb = kv0 + n * 16 + lh * 4;
#pragma unroll
          for (int r = 0; r < 4; ++r)
            if (kvb + r > qrow) sc[n][r] = MASKV;
        }
      }
      // in-register row max + cross-group reduce
      float mx = sc[0][0];
#pragma unroll
      for (int n = 0; n < 4; ++n)
#pragma unroll
        for (int r = 0; r < 4; ++r) mx = fmaxf(mx, sc[n][r]);
      mx = fmaxf(mx, __shfl_xor(mx, 16));
      mx = fmaxf(mx, __shfl_xor(mx, 32));
      // defer-max: skip rescale when growth <= 8 (P bounded by 2^8, f32-safe)
      if (!__all(mx <= m_st + 8.0f)) {
        float mn = fmaxf(m_st, mx);
        float resc = exp2_hw(m_st - mn);
        m_st = mn;
        l_st *= resc;
#pragma unroll
        for (int n2 = 0; n2 < 4; ++n2)
#pragma unroll
          for (int r = 0; r < 4; ++r) oa[n2][r] *= resc;
      }
      float s = 0.f;
#pragma unroll
      for (int n = 0; n < 4; ++n)
#pragma unroll
        for (int r = 0; r < 4; ++r) {
          float p = exp2_hw(sc[n][r] - m_st);
          sc[n][r] = p;
          s += p;
        }
      s += __shfl_xor(s, 16);
      s += __shfl_xor(s, 32);
      l_st += s;
      // P -> per-wave LDS tile P[q=lr][kv] (packed b64 writes, swizzled)
#pragma unroll
      for (int n = 0; n < 4; ++n) {
        int addr = lr * 128 + ((n * 32 + lh * 8) ^ ((lr & 7) << 4));
        uint2 val = { cvtpk_bf16(sc[n][0], sc[n][1]),
                      cvtpk_bf16(sc[n][2], sc[n][3]) };
        *(uint2*)(pw + addr) = val;
      }
      if (more) writeV(Vt[cur ^ 1]);      // stage next V^T (buffer free since barrier t-1)
      // P^T B-frags: col=q=lr, k=kv
      bf16x8 pa[2];
#pragma unroll
      for (int ks = 0; ks < 2; ++ks) {
        int o = lr * 128 + (((ks * 4 + lh) ^ (lr & 7)) << 4);
        pa[ks] = *(const bf16x8*)(pw + o);
      }
      // O^T += V^T * P^T : D[row=d][col=q]
      __builtin_amdgcn_s_setprio(1);
#pragma unroll
      for (int n2 = 0; n2 < 4; ++n2) {
        int row = n2 * 16 + lr;
        int o0 = row * 128 + ((((0 + lh) ^ (row & 7) ^ ((row >> 3) & 7)) & 7) << 4);
        int o1 = row * 128 + ((((4 + lh) ^ (row & 7) ^ ((row >> 3) & 7)) & 7) << 4);
        bf16x8 vf0 = *(const bf16x8*)((const char*)Vt[cur] + o0);
        bf16x8 vf1 = *(const bf16x8*)((const char*)Vt[cur] + o1);
        oa[n2] = __builtin_amdgcn_mfma_f32_16x16x32_bf16(vf0, pa[0], oa[n2], 0, 0, 0);
        oa[n2] = __builtin_amdgcn_mfma_f32_16x16x32_bf16(vf1, pa[1], oa[n2], 0, 0, 0);
      }
      __builtin_amdgcn_s_setprio(0);
      __syncthreads();
      cur ^= 1;
    }
    // epilogue: O = oa / l (lane-local), Z[(b*2048+q)*1024 + h*64 + d], 8B stores.
    float inv = 1.0f / l_st;
    int q = q0 + wv * 16 + lr;
    bf16* zb = Z + ((long)b * 2048 + q) * 1024 + h * 64 + lh * 4;
#pragma unroll
    for (int n2 = 0; n2 < 4; ++n2) {
      uint2 o2 = { cvtpk_bf16(oa[n2][0] * inv, oa[n2][1] * inv),
                   cvtpk_bf16(oa[n2][2] * inv, oa[n2][3] * inv) };
      *(uint2*)(zb + n2 * 16) = o2;
    }
    // loop ends: last tile's __syncthreads guarantees Vt free for next half's prologue
  }
}

// ---------------- launch ----------------
extern "C" void kernel_launch(void* const* d_in, const int* in_sizes, int n_in,
                              void* d_out, int out_size, void* d_ws, size_t ws_size,
                              hipStream_t stream) {
  const float* resid = (const float*)d_in[0];
  const float* WQ = (const float*)d_in[1];
  const float* WK = (const float*)d_in[2];
  const float* WV = (const float*)d_in[3];
  const float* WO = (const float*)d_in[4];
  const float* bQ = (const float*)d_in[5];
  const float* bK = (const float*)d_in[6];
  const float* bV = (const float*)d_in[7];
  const float* bO = (const float*)d_in[8];
  char* ws = (char*)d_ws;
  // layout (with aliasing): [Xb|Z 16.78MB][Wqkv|Wot 6.29MB][bias 16KB][QKVo 50.33MB] = 73.4MB
  bf16*  Xb      = (bf16*)ws;
  bf16*  Z       = (bf16*)ws;                      // aliases Xb (dead after QKV GEMM)
  bf16*  Wqkv    = (bf16*)(ws + 16777216);
  bf16*  Wot     = (bf16*)(ws + 16777216);         // aliases Wqkv (dead after QKV GEMM)
  float* biasqkv = (float*)(ws + 23068672);
  bf16*  QKVo    = (bf16*)(ws + 23085056);

  pack_x<<<4096, 256, 0, stream>>>(resid, Xb);
  pack_w<<<768, 256, 0, stream>>>(WQ, WK, WV, Wqkv);
  pack_bias<<<12, 256, 0, stream>>>(bQ, bK, bV, biasqkv);
  gemm_bt<0><<<dim3(24, 64), 256, 0, stream>>>(Xb, Wqkv, biasqkv, QKVo, 8192, 3072, 1024);
  pack_wo<<<256, 256, 0, stream>>>(WO, Wot);       // after gemm<0> has consumed Wqkv
  flash<<<1024, 256, 0, stream>>>(QKVo, Z);        // writes over Xb (already consumed)
  gemm_bt<1><<<dim3(8, 64), 256, 0, stream>>>(Z, Wot, bO, d_out, 8192, 1024, 1024);
}

// Round 7
// 264.775 us; speedup vs baseline: 1.2215x; 1.2215x over previous
//
#include <hip/hip_runtime.h>

typedef __bf16 bf16;
typedef __attribute__((ext_vector_type(8))) __bf16 bf16x8;
typedef __attribute__((ext_vector_type(4))) float f32x4;

// async global->LDS, 16B per lane. LDS dest must be wave-uniform base; HW writes
// base + lane*16. Swizzled layouts are achieved by pre-swizzling the global src.
__device__ __forceinline__ void gload_lds16(const void* g, void* l) {
  __builtin_amdgcn_global_load_lds(
      (const __attribute__((address_space(1))) unsigned int*)(g),
      (__attribute__((address_space(3))) unsigned int*)(l),
      16, 0, 0);
}

__device__ __forceinline__ float exp2_hw(float x) {  // v_exp_f32 = 2^x, pure VALU asm
  float r; asm("v_exp_f32 %0, %1" : "=v"(r) : "v"(x)); return r;
}
__device__ __forceinline__ unsigned cvtpk_bf16(float a, float b) {  // lo=a, hi=b
  unsigned r; asm("v_cvt_pk_bf16_f32 %0, %1, %2" : "=v"(r) : "v"(a), "v"(b)); return r;
}

#define QSCALE 0.1803368867f   // 0.125 * log2(e), folded into W_Q/b_Q at pack time

// ---------------- pack kernels ----------------

// resid fp32 -> bf16, vectorized 8/thread. n = 8388608 = 4096*256*8 exactly.
__global__ __launch_bounds__(256) void pack_x(const float* __restrict__ x, bf16* __restrict__ o) {
  int i = (blockIdx.x * 256 + threadIdx.x) * 8;
  float4 a = *(const float4*)(x + i);
  float4 b = *(const float4*)(x + i + 4);
  bf16x8 v;
  v[0] = (bf16)a.x; v[1] = (bf16)a.y; v[2] = (bf16)a.z; v[3] = (bf16)a.w;
  v[4] = (bf16)b.x; v[5] = (bf16)b.y; v[6] = (bf16)b.z; v[7] = (bf16)b.w;
  *(bf16x8*)(o + i) = v;
}

// W_{Q,K,V}[h][k][d] (fp32) -> Wt[n=p*1024+h*64+d][k] (bf16, B^T layout), 64x64 LDS transpose tiles.
// W_Q pre-scaled by QSCALE so attention scores come out in log2 domain directly.
__global__ __launch_bounds__(256) void pack_w(const float* __restrict__ WQ, const float* __restrict__ WK,
                                              const float* __restrict__ WV, bf16* __restrict__ Wt) {
  int bid = blockIdx.x;                 // 768 = 3 * 16h * 16k-tiles
  int p = bid >> 8, h = (bid >> 4) & 15, k0 = (bid & 15) * 64;
  const float* src = (p == 0 ? WQ : p == 1 ? WK : WV) + h * 65536;
  float scl = (p == 0) ? QSCALE : 1.0f;
  __shared__ float tile[64][65];
  int t = threadIdx.x, c = t & 63, r4 = t >> 6;
#pragma unroll
  for (int rr = 0; rr < 16; ++rr) {
    int k = r4 + rr * 4;
    tile[k][c] = src[(k0 + k) * 64 + c];   // coalesced read along d
  }
  __syncthreads();
#pragma unroll
  for (int rr = 0; rr < 16; ++rr) {
    int d = r4 + rr * 4;
    Wt[(p * 1024 + h * 64 + d) * 1024 + k0 + c] = (bf16)(tile[c][d] * scl);  // coalesced write along k
  }
}

// W_O viewed as [hd=1024][m=1024] -> Wo_t[m][hd]
__global__ __launch_bounds__(256) void pack_wo(const float* __restrict__ WO, bf16* __restrict__ Wt) {
  int bid = blockIdx.x;                 // 256 = 16 hd-tiles * 16 m-tiles
  int r0 = (bid >> 4) * 64, c0 = (bid & 15) * 64;
  __shared__ float tile[64][65];
  int t = threadIdx.x, c = t & 63, r4 = t >> 6;
#pragma unroll
  for (int rr = 0; rr < 16; ++rr) {
    int r = r4 + rr * 4;
    tile[r][c] = WO[(r0 + r) * 1024 + c0 + c];
  }
  __syncthreads();
#pragma unroll
  for (int rr = 0; rr < 16; ++rr) {
    int m = r4 + rr * 4;
    Wt[(c0 + m) * 1024 + r0 + c] = (bf16)tile[c][m];
  }
}

__global__ __launch_bounds__(256) void pack_bias(const float* __restrict__ bQ, const float* __restrict__ bK,
                                                 const float* __restrict__ bV, float* __restrict__ o) {
  int i = blockIdx.x * 256 + threadIdx.x;
  if (i < 3072) {
    int p = i >> 10, j = i & 1023;
    float v = (p == 0 ? bQ : p == 1 ? bK : bV)[j];
    o[i] = (p == 0) ? v * QSCALE : v;
  }
}

// ---------------- GEMM: C[M,N] = A[M,K] * Bt[N,K]^T + bias ----------------
template <int OUTF32>
__global__ __launch_bounds__(256, 2) void gemm_bt(const bf16* __restrict__ A, const bf16* __restrict__ Bt,
                                                  const float* __restrict__ bias, void* __restrict__ Cv,
                                                  int M, int N, int K) {
  __shared__ bf16 As[128 * 64];
  __shared__ bf16 Bs[128 * 64];
  int tid = threadIdx.x;
  int wv = tid >> 6, ln = tid & 63, lr = ln & 15, lh = ln >> 4;
  int wr = wv >> 1, wc = wv & 1;
  int row0 = blockIdx.y * 128, col0 = blockIdx.x * 128;
  int ss = (ln & 7) ^ (ln >> 3);
  const char* ga = (const char*)(A + (long)(row0 + wv * 32 + (ln >> 3)) * K) + ss * 16;
  const char* gb = (const char*)(Bt + (long)(col0 + wv * 32 + (ln >> 3)) * K) + ss * 16;
  long rowskip = (long)8 * K * 2;
  f32x4 acc[4][4] = {};
  for (int k0 = 0; k0 < K; k0 += 64) {
#pragma unroll
    for (int i = 0; i < 4; ++i) {
      gload_lds16(ga + (long)k0 * 2 + i * rowskip, (char*)As + (wv * 32 + i * 8) * 128);
      gload_lds16(gb + (long)k0 * 2 + i * rowskip, (char*)Bs + (wv * 32 + i * 8) * 128);
    }
    __syncthreads();
    bf16x8 af[4][2], bfr[4][2];
#pragma unroll
    for (int mi = 0; mi < 4; ++mi)
#pragma unroll
      for (int ks = 0; ks < 2; ++ks) {
        int row = wr * 64 + mi * 16 + lr;
        int o = row * 128 + (((ks * 4 + lh) ^ (row & 7)) << 4);
        af[mi][ks] = *(const bf16x8*)((const char*)As + o);
      }
#pragma unroll
    for (int ni = 0; ni < 4; ++ni)
#pragma unroll
      for (int ks = 0; ks < 2; ++ks) {
        int row = wc * 64 + ni * 16 + lr;
        int o = row * 128 + (((ks * 4 + lh) ^ (row & 7)) << 4);
        bfr[ni][ks] = *(const bf16x8*)((const char*)Bs + o);
      }
    __builtin_amdgcn_s_setprio(1);
#pragma unroll
    for (int ks = 0; ks < 2; ++ks)
#pragma unroll
      for (int mi = 0; mi < 4; ++mi)
#pragma unroll
        for (int ni = 0; ni < 4; ++ni)
          acc[mi][ni] = __builtin_amdgcn_mfma_f32_16x16x32_bf16(af[mi][ks], bfr[ni][ks], acc[mi][ni], 0, 0, 0);
    __builtin_amdgcn_s_setprio(0);
    __syncthreads();
  }
#pragma unroll
  for (int mi = 0; mi < 4; ++mi) {
    int row = row0 + wr * 64 + mi * 16 + lh * 4;
#pragma unroll
    for (int ni = 0; ni < 4; ++ni) {
      int col = col0 + wc * 64 + ni * 16 + lr;
      float bvv = bias[col];
#pragma unroll
      for (int r = 0; r < 4; ++r) {
        float v = acc[mi][ni][r] + bvv;
        if (OUTF32) ((float*)Cv)[(long)(row + r) * N + col] = v;
        else        ((bf16*)Cv)[(long)(row + r) * N + col] = (bf16)v;
      }
    }
  }
}

// ---------------- flash attention (swapped-operand, balanced 128-row pairs) ----------------
// grid = 512 = 64 bh * 8 pairs. Each block: 4 waves x 32 q-rows (128-row q-tile),
// processes TWO q-tiles sequentially: qt = pair and 15-pair -> exactly 34 kv-tile
// units per block; all 512 blocks identical, 2 blocks/CU for the whole kernel.
// S^T = mfma(A=K, B=Q): lane owns q=lr, 16 kv regs -> in-register softmax reduce.
// Q pre-scaled (log2 domain) at pack time. K direct from global (L2-resident).
// V^T in LDS double-buffered. P via per-wave swizzled LDS tile.
// PV = mfma(A=V^T, B=P^T) -> O^T, lane-local l. Defer-max (T13, THR=8 log2).
__global__ __launch_bounds__(256, 2) void flash(const bf16* __restrict__ Qkv, bf16* __restrict__ Z) {
  __shared__ bf16 Vt[2][64 * 64];        // [d][kv] V^T, swizzle f(d)=(d&7)^(d>>3)
  __shared__ unsigned char Pl[4][4096];  // per-wave P[q=32][kv=64] bf16, swizzle row&7
  const float MASKV = -144269.5041f;     // -1e5 * log2(e)
  int bid = blockIdx.x;
  int pair = bid >> 6;                         // 0..7
  int bh = (bid & 7) * 8 + ((bid >> 3) & 7);   // same-bh -> same XCD (bid%8)
  int b = bh >> 4, h = bh & 15;
  int tid = threadIdx.x;
  int wv = tid >> 6, ln = tid & 63, lr = ln & 15, lh = ln >> 4;
  const bf16* Qg = Qkv + (long)b * 2048 * 3072 + h * 64;
  const bf16* Kg = Qg + 1024;
  const bf16* Vg = Qg + 2048;
  int vs0 = (tid >> 3) * 2, vd0 = (tid & 7) * 8;
  char* pw = (char*)Pl[wv];

  bf16x8 v0, v1;
  auto loadV = [&](int kvrow0) {
    v0 = *(const bf16x8*)(Vg + (long)(kvrow0 + vs0) * 3072 + vd0);
    v1 = *(const bf16x8*)(Vg + (long)(kvrow0 + vs0 + 1) * 3072 + vd0);
  };
  auto writeV = [&](bf16* vd) {
#pragma unroll
    for (int j = 0; j < 8; ++j) {
      int d = vd0 + j;
      int o = (d * 128 + vs0 * 2) ^ ((((d & 7) ^ (d >> 3)) & 7) << 4);
      unsigned int pk = (unsigned int)__builtin_bit_cast(unsigned short, (bf16)v0[j])
                      | ((unsigned int)__builtin_bit_cast(unsigned short, (bf16)v1[j]) << 16);
      *(unsigned int*)((char*)vd + o) = pk;
    }
  };

#pragma unroll 1
  for (int half = 0; half < 2; ++half) {
    int qt = half ? 15 - pair : pair;    // balanced: 2(pair+1) + 2(16-pair-1) ... = 34 units
    int q0 = qt * 128;
    int nt = 2 * (qt + 1);
    // prologue: stage V tile 0, load Q frags for this q-tile
    loadV(0);
    bf16x8 bq[2][2];
#pragma unroll
    for (int mi = 0; mi < 2; ++mi)
#pragma unroll
      for (int ks = 0; ks < 2; ++ks)
        bq[mi][ks] = *(const bf16x8*)(Qg + (long)(q0 + wv * 32 + mi * 16 + lr) * 3072 + ks * 32 + lh * 8);
    writeV(Vt[0]);
    __syncthreads();

    f32x4 oa[4][2] = {};                 // oa[n2=dblk][mi]: O^T[d][q]
    float m_st[2], l_st[2];
    m_st[0] = m_st[1] = -1e30f;
    l_st[0] = l_st[1] = 0.f;

    int cur = 0;
    for (int t = 0; t < nt; ++t) {
      int kv0 = t * 64;
      bool more = (t + 1 < nt);
      // K A-frags for THIS tile, direct from global (L2-hot)
      bf16x8 kf[4][2];
#pragma unroll
      for (int n = 0; n < 4; ++n)
#pragma unroll
        for (int ks = 0; ks < 2; ++ks)
          kf[n][ks] = *(const bf16x8*)(Kg + (long)(kv0 + n * 16 + lr) * 3072 + ks * 32 + lh * 8);
      if (more) loadV(kv0 + 64);         // next tile's V, consumed ~600cy later
      // S^T = K * Q^T : D[row=kv][col=q], already in log2 domain (Q pre-scaled)
      f32x4 sc[2][4];
      __builtin_amdgcn_s_setprio(1);
#pragma unroll
      for (int mi = 0; mi < 2; ++mi)
#pragma unroll
        for (int n = 0; n < 4; ++n) {
          f32x4 zacc = {0.f, 0.f, 0.f, 0.f};
          zacc = __builtin_amdgcn_mfma_f32_16x16x32_bf16(kf[n][0], bq[mi][0], zacc, 0, 0, 0);
          zacc = __builtin_amdgcn_mfma_f32_16x16x32_bf16(kf[n][1], bq[mi][1], zacc, 0, 0, 0);
          sc[mi][n] = zacc;
        }
      __builtin_amdgcn_s_setprio(0);
      // causal mask: only the last two (diagonal-straddling) tiles need it
      if (kv0 + 63 > q0) {
#pragma unroll
        for (int mi = 0; mi < 2; ++mi) {
          int qrow = q0 + wv * 32 + mi * 16 + lr;
#pragma unroll
          for (int n = 0; n < 4; ++n) {
            int kvb = kv0 + n * 16 + lh * 4;
#pragma unroll
            for (int r = 0; r < 4; ++r)
              if (kvb + r > qrow) sc[mi][n][r] = MASKV;
          }
        }
      }
      // per-q-row softmax: in-register max over 16 regs + xor16/xor32 reduce
#pragma unroll
      for (int mi = 0; mi < 2; ++mi) {
        float mx = sc[mi][0][0];
#pragma unroll
        for (int n = 0; n < 4; ++n)
#pragma unroll
          for (int r = 0; r < 4; ++r) mx = fmaxf(mx, sc[mi][n][r]);
        mx = fmaxf(mx, __shfl_xor(mx, 16));
        mx = fmaxf(mx, __shfl_xor(mx, 32));
        // defer-max: skip rescale while growth <= 8 (P bounded by 2^8, safe)
        if (!__all(mx <= m_st[mi] + 8.0f)) {
          float mn = fmaxf(m_st[mi], mx);
          float resc = exp2_hw(m_st[mi] - mn);
          m_st[mi] = mn;
          l_st[mi] *= resc;
#pragma unroll
          for (int n2 = 0; n2 < 4; ++n2)
#pragma unroll
            for (int r = 0; r < 4; ++r) oa[n2][mi][r] *= resc;
        }
        float s = 0.f;
#pragma unroll
        for (int n = 0; n < 4; ++n)
#pragma unroll
          for (int r = 0; r < 4; ++r) {
            float p = exp2_hw(sc[mi][n][r] - m_st[mi]);
            sc[mi][n][r] = p;
            s += p;
          }
        s += __shfl_xor(s, 16);
        s += __shfl_xor(s, 32);
        l_st[mi] += s;
      }
      // P -> per-wave LDS tile P[q][kv] (packed b64 writes, swizzled), no barrier needed
#pragma unroll
      for (int mi = 0; mi < 2; ++mi) {
        int row = mi * 16 + lr;
#pragma unroll
        for (int n = 0; n < 4; ++n) {
          int addr = row * 128 + ((n * 32 + lh * 8) ^ ((row & 7) << 4));
          uint2 val = { cvtpk_bf16(sc[mi][n][0], sc[mi][n][1]),
                        cvtpk_bf16(sc[mi][n][2], sc[mi][n][3]) };
          *(uint2*)(pw + addr) = val;
        }
      }
      if (more) writeV(Vt[cur ^ 1]);     // stage next V^T into other buffer
      // P^T B-frags: col=q=lr(+mi*16), k=kv
      bf16x8 pa[2][2];
#pragma unroll
      for (int mi = 0; mi < 2; ++mi)
#pragma unroll
        for (int ks = 0; ks < 2; ++ks) {
          int row = mi * 16 + lr;
          int o = row * 128 + (((ks * 4 + lh) ^ (row & 7)) << 4);
          pa[mi][ks] = *(const bf16x8*)(pw + o);
        }
      // O^T += V^T * P^T : D[row=d][col=q]
      __builtin_amdgcn_s_setprio(1);
#pragma unroll
      for (int n2 = 0; n2 < 4; ++n2) {
        int row = n2 * 16 + lr;
        int o0 = row * 128 + ((((0 + lh) ^ (row & 7) ^ ((row >> 3) & 7)) & 7) << 4);
        int o1 = row * 128 + ((((4 + lh) ^ (row & 7) ^ ((row >> 3) & 7)) & 7) << 4);
        bf16x8 vf0 = *(const bf16x8*)((const char*)Vt[cur] + o0);
        bf16x8 vf1 = *(const bf16x8*)((const char*)Vt[cur] + o1);
#pragma unroll
        for (int mi = 0; mi < 2; ++mi) {
          oa[n2][mi] = __builtin_amdgcn_mfma_f32_16x16x32_bf16(vf0, pa[mi][0], oa[n2][mi], 0, 0, 0);
          oa[n2][mi] = __builtin_amdgcn_mfma_f32_16x16x32_bf16(vf1, pa[mi][1], oa[n2][mi], 0, 0, 0);
        }
      }
      __builtin_amdgcn_s_setprio(0);
      __syncthreads();
      cur ^= 1;
    }
    // epilogue: O = oa / l, lane-local l (q=lr). Z[(b*2048+q)*1024 + h*64 + d], 8B stores.
#pragma unroll
    for (int mi = 0; mi < 2; ++mi) {
      float inv = 1.0f / l_st[mi];
      int q = q0 + wv * 32 + mi * 16 + lr;
      bf16* zb = Z + ((long)b * 2048 + q) * 1024 + h * 64 + lh * 4;
#pragma unroll
      for (int n2 = 0; n2 < 4; ++n2) {
        uint2 o2 = { cvtpk_bf16(oa[n2][mi][0] * inv, oa[n2][mi][1] * inv),
                     cvtpk_bf16(oa[n2][mi][2] * inv, oa[n2][mi][3] * inv) };
        *(uint2*)(zb + n2 * 16) = o2;
      }
    }
    // last tile's __syncthreads guarantees Vt/Pl free for next half's prologue
  }
}

// ---------------- launch ----------------
extern "C" void kernel_launch(void* const* d_in, const int* in_sizes, int n_in,
                              void* d_out, int out_size, void* d_ws, size_t ws_size,
                              hipStream_t stream) {
  const float* resid = (const float*)d_in[0];
  const float* WQ = (const float*)d_in[1];
  const float* WK = (const float*)d_in[2];
  const float* WV = (const float*)d_in[3];
  const float* WO = (const float*)d_in[4];
  const float* bQ = (const float*)d_in[5];
  const float* bK = (const float*)d_in[6];
  const float* bV = (const float*)d_in[7];
  const float* bO = (const float*)d_in[8];
  char* ws = (char*)d_ws;
  // layout (with aliasing): [Xb|Z 16.78MB][Wqkv|Wot 6.29MB][bias 16KB][QKVo 50.33MB] = 73.4MB
  bf16*  Xb      = (bf16*)ws;
  bf16*  Z       = (bf16*)ws;                      // aliases Xb (dead after QKV GEMM)
  bf16*  Wqkv    = (bf16*)(ws + 16777216);
  bf16*  Wot     = (bf16*)(ws + 16777216);         // aliases Wqkv (dead after QKV GEMM)
  float* biasqkv = (float*)(ws + 23068672);
  bf16*  QKVo    = (bf16*)(ws + 23085056);

  pack_x<<<4096, 256, 0, stream>>>(resid, Xb);
  pack_w<<<768, 256, 0, stream>>>(WQ, WK, WV, Wqkv);
  pack_bias<<<12, 256, 0, stream>>>(bQ, bK, bV, biasqkv);
  gemm_bt<0><<<dim3(24, 64), 256, 0, stream>>>(Xb, Wqkv, biasqkv, QKVo, 8192, 3072, 1024);
  pack_wo<<<256, 256, 0, stream>>>(WO, Wot);       // after gemm<0> has consumed Wqkv
  flash<<<512, 256, 0, stream>>>(QKVo, Z);         // writes over Xb (already consumed)
  gemm_bt<1><<<dim3(8, 64), 256, 0, stream>>>(Z, Wot, bO, d_out, 8192, 1024, 1024);
}